// Round 7
// baseline (116.660 us; speedup 1.0000x reference)
//
#include <hip/hip_runtime.h>

#define THREADS 256
#define QPT 16             // queries per thread, scalar regs
#define NPTS 8192
#define BATCH 4

// partials ws layout: [S][2*BATCH][NPTS] float
//   S=64 -> 16.78 MB (preferred, 1024 blocks); S=32 -> 8.39 MB fallback (proven fit)

template <int S>
__global__ __launch_bounds__(THREADS, 4) void chamfer_main_t(
    const float* __restrict__ p1, const float* __restrict__ p2,
    float* __restrict__ partials)
{
    constexpr int SLICE = NPTS / S;      // targets per block
    const int tid  = threadIdx.x;
    const int dirb = blockIdx.z;         // 0..7 : dir*4 + batch
    const int dir  = dirb >> 2;
    const int b    = dirb & 3;
    const int qbase = blockIdx.x * (THREADS * QPT);
    const int tbase = blockIdx.y * SLICE;

    const float* __restrict__ qsrc = (dir == 0) ? p1 : p2;
    const float* __restrict__ tsrc = (dir == 0) ? p2 : p1;

    // ---- stage transformed targets into LDS: (-2x, -2y, -2z, |t|^2) ----
    __shared__ float4 tgt[SLICE];
    {
        const float* tp = tsrc + ((size_t)b * NPTS + tbase) * 3;
        for (int k = tid; k < SLICE; k += THREADS) {
            float x = tp[k * 3 + 0];
            float y = tp[k * 3 + 1];
            float z = tp[k * 3 + 2];
            tgt[k] = make_float4(-2.0f * x, -2.0f * y, -2.0f * z,
                                 fmaf(x, x, fmaf(y, y, z * z)));
        }
    }

    // ---- load this thread's queries (scalar regs; ~90 VGPR total) ----
    float ax[QPT], ay[QPT], az[QPT], best[QPT];
#pragma unroll
    for (int j = 0; j < QPT; ++j) {
        const int q = qbase + j * THREADS + tid;
        const float* qp = qsrc + ((size_t)b * NPTS + q) * 3;
        ax[j] = qp[0]; ay[j] = qp[1]; az[j] = qp[2];
        best[j] = 3.0e38f;
    }

    __syncthreads();

    // ---- main loop: 2 targets/iter, 3.5 scalar VALU slots per pair ----
#pragma unroll 2
    for (int m = 0; m < SLICE; m += 2) {
        float4 ta = tgt[m];
        float4 tb = tgt[m + 1];
#pragma unroll
        for (int j = 0; j < QPT; ++j) {
            float da = fmaf(ax[j], ta.x, fmaf(ay[j], ta.y, fmaf(az[j], ta.z, ta.w)));
            float db = fmaf(ax[j], tb.x, fmaf(ay[j], tb.y, fmaf(az[j], tb.z, tb.w)));
            best[j] = fminf(fminf(best[j], da), db);   // -> v_min3_f32
        }
    }

    // ---- epilogue: + |q|^2 (recomputed), clamp, plain coalesced stores ----
    float* pbase = partials + (((size_t)blockIdx.y * 8 + dirb) * NPTS);
#pragma unroll
    for (int j = 0; j < QPT; ++j) {
        float a2 = fmaf(ax[j], ax[j], fmaf(ay[j], ay[j], az[j] * az[j]));
        float v = fmaxf(best[j] + a2, 0.0f);
        pbase[qbase + j * THREADS + tid] = v;
    }
}

// 65536 threads: each min-folds its (dirb,q) over S slices, block-sum + atomicAdd
template <int S>
__global__ __launch_bounds__(THREADS) void chamfer_reduce_t(
    const float* __restrict__ partials, float* __restrict__ out)
{
    const int i = blockIdx.x * THREADS + threadIdx.x;   // [0, 65536)
    const int dirb = i >> 13;
    const int q = i & (NPTS - 1);
    float v = 3.4e38f;
#pragma unroll 8
    for (int s = 0; s < S; ++s)
        v = fminf(v, partials[((size_t)s * 8 + dirb) * NPTS + q]);

    float sv = v;
#pragma unroll
    for (int off = 32; off >= 1; off >>= 1)
        sv += __shfl_down(sv, off, 64);
    __shared__ float partial[THREADS / 64];
    if ((threadIdx.x & 63) == 0) partial[threadIdx.x >> 6] = sv;
    __syncthreads();
    if (threadIdx.x == 0) {
        float tot = 0.0f;
#pragma unroll
        for (int w = 0; w < THREADS / 64; ++w) tot += partial[w];
        atomicAdd(out, tot * (1.0f / (BATCH * NPTS)));
    }
}

extern "C" void kernel_launch(void* const* d_in, const int* in_sizes, int n_in,
                              void* d_out, int out_size, void* d_ws, size_t ws_size,
                              hipStream_t stream) {
    const float* p1 = (const float*)d_in[0];
    const float* p2 = (const float*)d_in[1];
    float* out = (float*)d_out;
    float* partials = (float*)d_ws;

    hipMemsetAsync(d_out, 0, sizeof(float), stream);

    const size_t need64 = (size_t)64 * 8 * NPTS * 4;   // 16.78 MB
    if (ws_size >= need64) {
        dim3 grid(NPTS / (THREADS * QPT), 64, 2 * BATCH);   // 1024 blocks
        chamfer_main_t<64><<<grid, THREADS, 0, stream>>>(p1, p2, partials);
        chamfer_reduce_t<64><<<(2 * BATCH * NPTS) / THREADS, THREADS, 0, stream>>>(
            partials, out);
    } else {
        dim3 grid(NPTS / (THREADS * QPT), 32, 2 * BATCH);   // 512 blocks
        chamfer_main_t<32><<<grid, THREADS, 0, stream>>>(p1, p2, partials);
        chamfer_reduce_t<32><<<(2 * BATCH * NPTS) / THREADS, THREADS, 0, stream>>>(
            partials, out);
    }
}

// Round 8
// 114.639 us; speedup vs baseline: 1.0176x; 1.0176x over previous
//
#include <hip/hip_runtime.h>

#define THREADS 256
#define NPTS 8192
#define BATCH 4
#define NTILES (NPTS / 32)                 // 256 target tiles per dirb
#define NTASKS (2 * BATCH * (NPTS / 32))   // 2048 wave tasks
#define NBLOCKS (NTASKS / 4)               // 512 blocks

typedef short bf16x8 __attribute__((ext_vector_type(8)));
typedef float f32x16 __attribute__((ext_vector_type(16)));

#define BF16_ONE ((unsigned short)0x3F80)

__device__ __forceinline__ unsigned short bf16_rne(float x) {
    unsigned int u = __float_as_uint(x);
    unsigned int r = u + 0x7FFFu + ((u >> 16) & 1u);
    return (unsigned short)(r >> 16);
}
__device__ __forceinline__ float bf16_to_f(unsigned short h) {
    return __uint_as_float(((unsigned int)h) << 16);
}

// ws layout: atab[8][NPTS][16] bf16 (2 MB) then btab[8][NPTS][16] bf16 (2 MB)
// A row (query q):  [xh,xh,xl,xl, yh,yh,yl,yl, zh,zh,zl,zl, q2h,q2l, 1, 1]
// B row (target t): [uh,ul,uh,ul, vh,vl,vh,vl, wh,wl,wh,wl, 1, 1, t2h,t2l]
//   u=-2tx v=-2ty w=-2tz ; sum(A[k]*B[k]) = |q|^2 + |t|^2 - 2 q.t  (exact to ~2^-18)

__global__ __launch_bounds__(THREADS) void chamfer_prep(
    const float* __restrict__ p1, const float* __restrict__ p2,
    unsigned short* __restrict__ atab, unsigned short* __restrict__ btab)
{
    const int i = blockIdx.x * THREADS + threadIdx.x;   // [0, 65536) = dirb*8192 + p
    const int dirb = i >> 13;
    const int p = i & (NPTS - 1);
    const int dir = dirb >> 2, b = dirb & 3;
    const float* __restrict__ qsrc = (dir == 0) ? p1 : p2;
    const float* __restrict__ tsrc = (dir == 0) ? p2 : p1;

    // ---- A row from query point ----
    {
        const float* qp = qsrc + ((size_t)b * NPTS + p) * 3;
        float x = qp[0], y = qp[1], z = qp[2];
        unsigned short xh = bf16_rne(x), yh = bf16_rne(y), zh = bf16_rne(z);
        unsigned short xl = bf16_rne(x - bf16_to_f(xh));
        unsigned short yl = bf16_rne(y - bf16_to_f(yh));
        unsigned short zl = bf16_rne(z - bf16_to_f(zh));
        float q2 = fmaf(x, x, fmaf(y, y, z * z));
        unsigned short q2h = bf16_rne(q2);
        unsigned short q2l = bf16_rne(q2 - bf16_to_f(q2h));
        unsigned short k[16] = {xh, xh, xl, xl, yh, yh, yl, yl,
                                zh, zh, zl, zl, q2h, q2l, BF16_ONE, BF16_ONE};
        uint4* dst = (uint4*)(atab + (size_t)i * 16);
        uint4 w0, w1;
        w0.x = (unsigned)k[0] | ((unsigned)k[1] << 16);
        w0.y = (unsigned)k[2] | ((unsigned)k[3] << 16);
        w0.z = (unsigned)k[4] | ((unsigned)k[5] << 16);
        w0.w = (unsigned)k[6] | ((unsigned)k[7] << 16);
        w1.x = (unsigned)k[8] | ((unsigned)k[9] << 16);
        w1.y = (unsigned)k[10] | ((unsigned)k[11] << 16);
        w1.z = (unsigned)k[12] | ((unsigned)k[13] << 16);
        w1.w = (unsigned)k[14] | ((unsigned)k[15] << 16);
        dst[0] = w0; dst[1] = w1;
    }
    // ---- B row from target point ----
    {
        const float* tp = tsrc + ((size_t)b * NPTS + p) * 3;
        float x = tp[0], y = tp[1], z = tp[2];
        float u = -2.0f * x, v = -2.0f * y, w = -2.0f * z;
        unsigned short uh = bf16_rne(u), vh = bf16_rne(v), wh = bf16_rne(w);
        unsigned short ul = bf16_rne(u - bf16_to_f(uh));
        unsigned short vl = bf16_rne(v - bf16_to_f(vh));
        unsigned short wl = bf16_rne(w - bf16_to_f(wh));
        float t2 = fmaf(x, x, fmaf(y, y, z * z));
        unsigned short t2h = bf16_rne(t2);
        unsigned short t2l = bf16_rne(t2 - bf16_to_f(t2h));
        unsigned short k[16] = {uh, ul, uh, ul, vh, vl, vh, vl,
                                wh, wl, wh, wl, BF16_ONE, BF16_ONE, t2h, t2l};
        uint4* dst = (uint4*)(btab + (size_t)i * 16);
        uint4 w0, w1;
        w0.x = (unsigned)k[0] | ((unsigned)k[1] << 16);
        w0.y = (unsigned)k[2] | ((unsigned)k[3] << 16);
        w0.z = (unsigned)k[4] | ((unsigned)k[5] << 16);
        w0.w = (unsigned)k[6] | ((unsigned)k[7] << 16);
        w1.x = (unsigned)k[8] | ((unsigned)k[9] << 16);
        w1.y = (unsigned)k[10] | ((unsigned)k[11] << 16);
        w1.z = (unsigned)k[12] | ((unsigned)k[13] << 16);
        w1.w = (unsigned)k[14] | ((unsigned)k[15] << 16);
        dst[0] = w0; dst[1] = w1;
    }
}

// One wave = 32 queries x ALL 8192 targets of its dirb. Per-query min is final.
// A-frag (32x16): lane L holds row m=L&31, k=(L>>5)*8+j  -> af[point*2 + (L>>5)]
// B-frag (16x32): lane L holds col n=L&31, k=(L>>5)*8+j  -> bf[point*2 + (L>>5)]
// C/D (m74/m101): col = lane&31, row = (reg&3) + 8*(reg>>2) + 4*(lane>>5)
__global__ __launch_bounds__(THREADS) void chamfer_mfma(
    const unsigned short* __restrict__ atab,
    const unsigned short* __restrict__ btab,
    float* __restrict__ out)
{
    const int wid  = threadIdx.x >> 6;
    const int lane = threadIdx.x & 63;
    const int half = lane >> 5;
    const int ln   = lane & 31;
    const int task = blockIdx.x * 4 + wid;       // 0..2047 (4 waves of a block share dirb)
    const int dirb = task >> 8;
    const int g    = task & 255;                 // query group (32 queries)

    const bf16x8* __restrict__ af = (const bf16x8*)atab;
    const bf16x8* __restrict__ bfp = (const bf16x8*)btab
        + (size_t)dirb * NPTS * 2 + (size_t)ln * 2 + half;

    bf16x8 a = af[((size_t)dirb * NPTS + (size_t)g * 32 + ln) * 2 + half];

    f32x16 zc = {0.f, 0.f, 0.f, 0.f, 0.f, 0.f, 0.f, 0.f,
                 0.f, 0.f, 0.f, 0.f, 0.f, 0.f, 0.f, 0.f};
    float best[16];
#pragma unroll
    for (int r = 0; r < 16; ++r) best[r] = 3.0e38f;

#pragma unroll 2
    for (int t = 0; t < NTILES; ++t) {
        bf16x8 bfr = bfp[t * 64];   // wave reads a contiguous 1 KB tile (lane-permuted)
        f32x16 acc = __builtin_amdgcn_mfma_f32_32x32x16_bf16(a, bfr, zc, 0, 0, 0);
#pragma unroll
        for (int r = 0; r < 16; ++r) best[r] = fminf(best[r], acc[r]);
    }

    // cross-lane min over the 32 target-cols (xor masks stay within the 32-half)
#pragma unroll
    for (int m = 16; m >= 1; m >>= 1) {
#pragma unroll
        for (int r = 0; r < 16; ++r)
            best[r] = fminf(best[r], __shfl_xor(best[r], m, 64));
    }

    // clamp tiny negatives, sum this lane's 16 query-rows (replicated x32 per half)
    float s = 0.0f;
#pragma unroll
    for (int r = 0; r < 16; ++r) s += fmaxf(best[r], 0.0f);

    __shared__ float psum[8];          // 4 waves x 2 halves (16 rows each)
    if (ln == 0) psum[wid * 2 + half] = s;
    __syncthreads();
    if (threadIdx.x == 0) {
        float tot = 0.0f;
#pragma unroll
        for (int k = 0; k < 8; ++k) tot += psum[k];
        atomicAdd(out, tot * (1.0f / (BATCH * NPTS)));
    }
}

extern "C" void kernel_launch(void* const* d_in, const int* in_sizes, int n_in,
                              void* d_out, int out_size, void* d_ws, size_t ws_size,
                              hipStream_t stream) {
    const float* p1 = (const float*)d_in[0];
    const float* p2 = (const float*)d_in[1];
    float* out = (float*)d_out;

    unsigned short* atab = (unsigned short*)d_ws;                       // 2 MB
    unsigned short* btab = atab + (size_t)2 * BATCH * NPTS * 16;        // 2 MB

    hipMemsetAsync(d_out, 0, sizeof(float), stream);

    chamfer_prep<<<(2 * BATCH * NPTS) / THREADS, THREADS, 0, stream>>>(
        p1, p2, atab, btab);

    chamfer_mfma<<<NBLOCKS, THREADS, 0, stream>>>(atab, btab, out);
}